// Round 16
// baseline (168.014 us; speedup 1.0000x reference)
//
#include <hip/hip_runtime.h>
#include <hip/hip_bf16.h>
#include <stdint.h>

#define NQ 2048
#define NKV 2048
#define DIM 1024
#define INNER 1024
#define HEADS 16
#define DH 64
#define BATCH 2

typedef float f32x4 __attribute__((ext_vector_type(4)));
typedef float f32x16 __attribute__((ext_vector_type(16)));
typedef __bf16 bf16x8 __attribute__((ext_vector_type(8)));
typedef unsigned int u32x4 __attribute__((ext_vector_type(4)));

__device__ inline ushort f2b(float f) {
    uint32_t u = __builtin_bit_cast(uint32_t, f);
    u += 0x7fff + ((u >> 16) & 1);   // round-to-nearest-even
    return (ushort)(u >> 16);
}

__device__ inline uint pkbf16(float lo, float hi) {
    __hip_bfloat162 h = __float22bfloat162_rn(make_float2(lo, hi));
    uint r;
    __builtin_memcpy(&r, &h, 4);   // low 16 = bf16(lo), high 16 = bf16(hi)
    return r;
}

__device__ __forceinline__ void gload16(const void* g, void* lds) {
    __builtin_amdgcn_global_load_lds(
        (const __attribute__((address_space(1))) unsigned int*)g,
        (__attribute__((address_space(3))) unsigned int*)lds, 16, 0, 0);
}

// ---------------- fused prep: z<4 -> weight transpose+cvt slices; z==4 -> x/ctx convert ----------------
__global__ void prep(const float* __restrict__ x, const float* __restrict__ ctx,
                     const float* __restrict__ Wq, const float* __restrict__ Wkv,
                     const float* __restrict__ Wout,
                     ushort* __restrict__ xb, ushort* __restrict__ cb,
                     ushort* __restrict__ Wqt, ushort* __restrict__ Wkvt,
                     ushort* __restrict__ Woutt) {
    int z = blockIdx.z;
    if (z < 4) {
        __shared__ ushort tile[32][33];
        const float* src; ushort* dst; int C;
        if (z == 0)      { src = Wq;          dst = Wqt;                C = 1024; }
        else if (z == 1) { src = Wkv;         dst = Wkvt;               C = 2048; }
        else if (z == 2) { src = Wkv + 1024;  dst = Wkvt + 1024 * 1024; C = 2048; }
        else             { src = Wout;        dst = Woutt;              C = 1024; }
        int c0 = blockIdx.x * 32, r0 = blockIdx.y * 32;
        int tx = threadIdx.x, ty = threadIdx.y;   // 32 x 8
#pragma unroll
        for (int i = 0; i < 4; i++)
            tile[ty + i * 8][tx] = f2b(src[(size_t)(r0 + ty + i * 8) * C + c0 + tx]);
        __syncthreads();
#pragma unroll
        for (int i = 0; i < 4; i++)
            dst[(size_t)(c0 + ty + i * 8) * 1024 + r0 + tx] = tile[tx][ty + i * 8];
    } else {
        const int n4 = (BATCH * NQ * DIM) / 4;   // float4 count per tensor
        int fb = blockIdx.y * 32 + blockIdx.x;   // 0..1023
        int t = threadIdx.y * 32 + threadIdx.x;  // 0..255
        for (int i = fb * 256 + t; i < 2 * n4; i += 1024 * 256) {
            float4 v;
            if (i < n4) v = ((const float4*)x)[i];
            else        v = ((const float4*)ctx)[i - n4];
            ushort4 o;
            o.x = f2b(v.x); o.y = f2b(v.y); o.z = f2b(v.z); o.w = f2b(v.w);
            if (i < n4) ((ushort4*)xb)[i] = o;
            else        ((ushort4*)cb)[i - n4] = o;
        }
    }
}

// ---------------- fused q/kv GEMM: 768 blocks of 128x128, K=1024, triple-buffer 2-deep prefetch ----------------
__global__ __launch_bounds__(256) void gemm_qkv(const ushort* __restrict__ xb, const ushort* __restrict__ cb,
                                                const ushort* __restrict__ Wqt, const ushort* __restrict__ Wkvt,
                                                ushort* __restrict__ qb, ushort* __restrict__ kb,
                                                ushort* __restrict__ vtb, float qscale) {
    constexpr int K = 1024, NT = 32;
    __shared__ ushort lds[24576];   // 48KB: 3 bufs x (A 8KB + B 8KB); v-epilogue tile [128][136] reuses
    int flat = blockIdx.x;
    int swz = (flat & 7) * 96 + (flat >> 3);      // XCD-chunked, bijective (768 % 8 == 0)
    bool isq = swz < 256;
    const ushort *A, *Bt;
    int m0, n0;
    if (isq) { A = xb; Bt = Wqt;  m0 = (swz >> 3) * 128;  n0 = (swz & 7) * 128; }
    else     { int b2 = swz - 256; A = cb; Bt = Wkvt; m0 = (b2 >> 4) * 128; n0 = (b2 & 15) * 128; }
    int t = threadIdx.x, l = t & 63, w = t >> 6;
    int wr = w >> 1, wc = w & 1;
    int lg = l >> 4, lc = l & 15;
    f32x4 acc[4][4] = {};

    auto stage = [&](int buf, int k0) {
#pragma unroll
        for (int i = 0; i < 2; i++) {
            int s = w + i * 4;
            gload16(A + (size_t)(m0 + (s & 1) * 64 + l) * K + k0 + (s >> 1) * 8, &lds[buf * 8192 + s * 512]);
            gload16(Bt + (size_t)(n0 + (s & 1) * 64 + l) * K + k0 + (s >> 1) * 8, &lds[buf * 8192 + 4096 + s * 512]);
        }
    };

    stage(0, 0);
    stage(1, 32);
    for (int tt = 0; tt < NT; ++tt) {
        int cur = tt % 3;
        if (tt + 2 < NT) {
            stage((tt + 2) % 3, (tt + 2) * 32);   // 2-deep prefetch, stays in flight
            asm volatile("s_waitcnt vmcnt(8)" ::: "memory");   // oldest 4 (cur tile) done
        } else if (tt + 1 < NT) {
            asm volatile("s_waitcnt vmcnt(4)" ::: "memory");
        } else {
            asm volatile("s_waitcnt vmcnt(0)" ::: "memory");
        }
        __builtin_amdgcn_s_barrier();
        asm volatile("" ::: "memory");
        bf16x8 af[4], bf[4];
#pragma unroll
        for (int mi = 0; mi < 4; mi++)
            af[mi] = *(const bf16x8*)&lds[cur * 8192 + (lg * 128 + wr * 64 + mi * 16 + lc) * 8];
#pragma unroll
        for (int ni = 0; ni < 4; ni++)
            bf[ni] = *(const bf16x8*)&lds[cur * 8192 + 4096 + (lg * 128 + wc * 64 + ni * 16 + lc) * 8];
        __builtin_amdgcn_s_setprio(1);
#pragma unroll
        for (int mi = 0; mi < 4; mi++)
#pragma unroll
            for (int ni = 0; ni < 4; ni++)
                acc[mi][ni] = __builtin_amdgcn_mfma_f32_16x16x32_bf16(af[mi], bf[ni], acc[mi][ni], 0, 0, 0);
        __builtin_amdgcn_s_setprio(0);
        asm volatile("s_waitcnt lgkmcnt(0)" ::: "memory");
        __builtin_amdgcn_s_barrier();
        asm volatile("" ::: "memory");
    }
    if (isq) {
#pragma unroll
        for (int mi = 0; mi < 4; mi++)
#pragma unroll
            for (int ni = 0; ni < 4; ni++)
#pragma unroll
                for (int r = 0; r < 4; r++) {
                    int m = m0 + wr * 64 + mi * 16 + lg * 4 + r;
                    int n = n0 + wc * 64 + ni * 16 + lc;
                    qb[(size_t)m * 1024 + n] = f2b(acc[mi][ni][r] * qscale);
                }
    } else if (n0 < 1024) {      // k half: row-major
#pragma unroll
        for (int mi = 0; mi < 4; mi++)
#pragma unroll
            for (int ni = 0; ni < 4; ni++)
#pragma unroll
                for (int r = 0; r < 4; r++) {
                    int m = m0 + wr * 64 + mi * 16 + lg * 4 + r;
                    int n = n0 + wc * 64 + ni * 16 + lc;
                    kb[(size_t)m * 1024 + n] = f2b(acc[mi][ni][r]);
                }
    } else {                     // v half: LDS transpose -> coalesced vtb[b][h][d][kv] stores
        int b = m0 >> 11, kv0 = m0 & 2047;
        int h0 = (n0 - 1024) >> 6;                // block covers heads h0, h0+1
#pragma unroll
        for (int mi = 0; mi < 4; mi++)
#pragma unroll
            for (int ni = 0; ni < 4; ni++)
#pragma unroll
                for (int r = 0; r < 4; r++) {
                    int ml = wr * 64 + mi * 16 + lg * 4 + r;    // kv-local 0..127
                    int nl = wc * 64 + ni * 16 + lc;            // n-local 0..127
                    lds[nl * 136 + ml] = f2b(acc[mi][ni][r]);
                }
        __syncthreads();
#pragma unroll
        for (int c = 0; c < 8; c++) {
            int idx = c * 256 + t;            // 0..2047
            int rrow = idx >> 4;              // n-local 0..127
            int chunk = idx & 15;             // 16B chunk along kv
            int h = h0 + (rrow >> 6), d = rrow & 63;
            u32x4 v = *(u32x4*)&lds[rrow * 136 + chunk * 8];
            *(u32x4*)&vtb[(((size_t)b * HEADS + h) * DH + d) * (size_t)NKV + kv0 + chunk * 8] = v;
        }
    }
}

// ---------------- out-proj GEMM: 512 blocks of 64x128, triple-buffer 2-deep, f32 out + bias ----------------
__global__ __launch_bounds__(256) void gemm_out(const ushort* __restrict__ A, const ushort* __restrict__ Bt,
                                                float* __restrict__ C0, const float* __restrict__ bias) {
    constexpr int K = 1024, NT = 32;
    __shared__ ushort lds[3][6144];   // per buf: A 64x32 (4KB) @0, B 128x32 (8KB) @2048
    int flat = blockIdx.x;
    int swz = (flat & 7) * 64 + (flat >> 3);      // XCD-chunked (512 % 8 == 0)
    int m0 = (swz >> 3) * 64, n0 = (swz & 7) * 128;
    int t = threadIdx.x, l = t & 63, w = t >> 6;
    int wr = w >> 1, wc = w & 1;
    int lg = l >> 4, lc = l & 15;
    f32x4 acc[2][4] = {};

    auto stage = [&](int buf, int k0) {
        gload16(A + (size_t)(m0 + l) * K + k0 + w * 8, &lds[buf][w * 512 + l * 8]);
#pragma unroll
        for (int i = 0; i < 2; i++) {
            int s = w + i * 4;
            gload16(Bt + (size_t)(n0 + (s & 1) * 64 + l) * K + k0 + (s >> 1) * 8, &lds[buf][2048 + s * 512]);
        }
    };

    stage(0, 0);
    stage(1, 32);
    for (int tt = 0; tt < NT; ++tt) {
        int cur = tt % 3;
        if (tt + 2 < NT) {
            stage((tt + 2) % 3, (tt + 2) * 32);
            asm volatile("s_waitcnt vmcnt(6)" ::: "memory");
        } else if (tt + 1 < NT) {
            asm volatile("s_waitcnt vmcnt(3)" ::: "memory");
        } else {
            asm volatile("s_waitcnt vmcnt(0)" ::: "memory");
        }
        __builtin_amdgcn_s_barrier();
        asm volatile("" ::: "memory");
        bf16x8 af[2], bf[4];
#pragma unroll
        for (int mi = 0; mi < 2; mi++)
            af[mi] = *(const bf16x8*)&lds[cur][(lg * 64 + wr * 32 + mi * 16 + lc) * 8];
#pragma unroll
        for (int ni = 0; ni < 4; ni++)
            bf[ni] = *(const bf16x8*)&lds[cur][2048 + (lg * 128 + wc * 64 + ni * 16 + lc) * 8];
        __builtin_amdgcn_s_setprio(1);
#pragma unroll
        for (int mi = 0; mi < 2; mi++)
#pragma unroll
            for (int ni = 0; ni < 4; ni++)
                acc[mi][ni] = __builtin_amdgcn_mfma_f32_16x16x32_bf16(af[mi], bf[ni], acc[mi][ni], 0, 0, 0);
        __builtin_amdgcn_s_setprio(0);
        asm volatile("s_waitcnt lgkmcnt(0)" ::: "memory");
        __builtin_amdgcn_s_barrier();
        asm volatile("" ::: "memory");
    }
#pragma unroll
    for (int mi = 0; mi < 2; mi++)
#pragma unroll
        for (int ni = 0; ni < 4; ni++)
#pragma unroll
            for (int r = 0; r < 4; r++) {
                int m = m0 + wr * 32 + mi * 16 + lg * 4 + r;
                int n = n0 + wc * 64 + ni * 16 + lc;
                C0[(size_t)m * 1024 + n] = acc[mi][ni][r] + bias[n];
            }
}

// ---------------- flash attention v9: 32x32 MFMA, in-reg P, T15 double-pipeline ----------------
// QBLK=128 (4 waves x 32 q), KVBLK=64, 4-buffer K/V. Iter tt: QK(tt+1) issued FIRST, then
// softmax+pack+PV(tt) runs while those MFMAs drain. Q frags direct from global. qb pre-scaled 0.125*log2e.
__global__ __launch_bounds__(256, 2) void attn7(const ushort* __restrict__ qb, const ushort* __restrict__ kb,
                                                const ushort* __restrict__ vtb, ushort* __restrict__ ob) {
    __shared__ ushort Ks[4][4096];       // [dc8][kv64][8] 8KB x4
    __shared__ ushort Vs[4][4096];       // [kvc8][d64][8] 8KB x4
    int flat = blockIdx.x;
    int swz = (flat & 7) * 64 + (flat >> 3);           // XCD-chunked (512 % 8 == 0)
    int qt = swz & 15, h = (swz >> 4) & 15, b = swz >> 8;
    int t = threadIdx.x, l = t & 63, w = t >> 6;
    int ll = l & 31, hi = l >> 5;
    const ushort* Qg = qb + (size_t)b * NQ * INNER + h * DH;
    const ushort* Kg = kb + (size_t)b * NKV * INNER + h * DH;
    const ushort* Vg = vtb + (((size_t)b * HEADS + h) * DH) * NKV;
    int q0 = qt * 128;
    constexpr int NT2 = NKV / 64;        // 32

    // Q fragments direct from global (one-time): q col = w*32+ll, d rows = (dchunk*2+hi)*8..+8
    bf16x8 qf[4];
#pragma unroll
    for (int dchunk = 0; dchunk < 4; dchunk++) {
        int dc = dchunk * 2 + hi;
        qf[dchunk] = *(const bf16x8*)&Qg[(size_t)(q0 + w * 32 + ll) * INNER + dc * 8];
    }
    auto stageKV = [&](int buf, int kv0) {
#pragma unroll
        for (int i = 0; i < 2; i++) {
            int s = w + i * 4;
            gload16(Kg + (size_t)(kv0 + l) * INNER + s * 8, &Ks[buf][s * 512]);
            gload16(Vg + (size_t)l * NKV + kv0 + s * 8, &Vs[buf][s * 512]);
        }
    };
    stageKV(0, 0); stageKV(1, 64); stageKV(2, 128);
    asm volatile("s_waitcnt vmcnt(8)" ::: "memory");   // qf + tile0 landed
    __builtin_amdgcn_s_barrier();
    asm volatile("" ::: "memory");

    f32x16 zf = {};
    auto qk = [&](f32x16& d0, f32x16& d1, int bufi) {
        d0 = zf; d1 = zf;
        __builtin_amdgcn_s_setprio(1);
#pragma unroll
        for (int dchunk = 0; dchunk < 4; dchunk++) {
            int dc = dchunk * 2 + hi;
            bf16x8 kf0 = *(const bf16x8*)&Ks[bufi][(dc * 64 + ll) * 8];
            bf16x8 kf1 = *(const bf16x8*)&Ks[bufi][(dc * 64 + 32 + ll) * 8];
            d0 = __builtin_amdgcn_mfma_f32_32x32x16_bf16(kf0, qf[dchunk], d0, 0, 0, 0);
            d1 = __builtin_amdgcn_mfma_f32_32x32x16_bf16(kf1, qf[dchunk], d1, 0, 0, 0);
        }
        __builtin_amdgcn_s_setprio(0);
    };

    f32x16 stA0, stA1, stB0, stB1;
    qk(stA0, stA1, 0);

    f32x16 o0 = {}, o1 = {};
    float m_ = -1e30f, s_ = 0.f;

    auto body = [&](f32x16& c0, f32x16& c1, f32x16& n0v, f32x16& n1v, int tt) {
        if (tt + 2 < NT2) { asm volatile("s_waitcnt vmcnt(4)" ::: "memory"); }   // tile tt+1 landed
        else              { asm volatile("s_waitcnt vmcnt(0)" ::: "memory"); }
        __builtin_amdgcn_s_barrier();     // all waves done with buf (tt-1)&3
        asm volatile("" ::: "memory");
        if (tt + 3 < NT2) stageKV((tt + 3) & 3, (tt + 3) * 64);
        if (tt + 1 < NT2) qk(n0v, n1v, (tt + 1) & 3);   // issue next-tile QK; drains under softmax

        // online softmax on tile tt (c0/c1): lane owns q = w*32+ll; kv rows split lane l / l^32
        float mx;
        {
            float a = fmaxf(fmaxf(c0[0], c0[1]), fmaxf(c0[2], c0[3]));
            float b2 = fmaxf(fmaxf(c0[4], c0[5]), fmaxf(c0[6], c0[7]));
            float c = fmaxf(fmaxf(c0[8], c0[9]), fmaxf(c0[10], c0[11]));
            float d = fmaxf(fmaxf(c0[12], c0[13]), fmaxf(c0[14], c0[15]));
            float e = fmaxf(fmaxf(c1[0], c1[1]), fmaxf(c1[2], c1[3]));
            float f = fmaxf(fmaxf(c1[4], c1[5]), fmaxf(c1[6], c1[7]));
            float g = fmaxf(fmaxf(c1[8], c1[9]), fmaxf(c1[10], c1[11]));
            float h2 = fmaxf(fmaxf(c1[12], c1[13]), fmaxf(c1[14], c1[15]));
            mx = fmaxf(fmaxf(fmaxf(a, b2), fmaxf(c, d)), fmaxf(fmaxf(e, f), fmaxf(g, h2)));
        }
        mx = fmaxf(mx, __shfl_xor(mx, 32));
        if (!__all(mx - m_ <= 8.f)) {        // defer-max (T13)
            float mn2 = fmaxf(m_, mx);
            float fac = __builtin_amdgcn_exp2f(m_ - mn2);
            m_ = mn2; s_ *= fac; o0 *= fac; o1 *= fac;
        }
        float mn = m_;
#pragma unroll
        for (int r = 0; r < 16; r++) c0[r] = __builtin_amdgcn_exp2f(c0[r] - mn);
#pragma unroll
        for (int r = 0; r < 16; r++) c1[r] = __builtin_amdgcn_exp2f(c1[r] - mn);
        float rs;
        {
            float a = (c0[0] + c0[1]) + (c0[2] + c0[3]);
            float b2 = (c0[4] + c0[5]) + (c0[6] + c0[7]);
            float c = (c0[8] + c0[9]) + (c0[10] + c0[11]);
            float d = (c0[12] + c0[13]) + (c0[14] + c0[15]);
            float e = (c1[0] + c1[1]) + (c1[2] + c1[3]);
            float f = (c1[4] + c1[5]) + (c1[6] + c1[7]);
            float g = (c1[8] + c1[9]) + (c1[10] + c1[11]);
            float h2 = (c1[12] + c1[13]) + (c1[14] + c1[15]);
            rs = ((a + b2) + (c + d)) + ((e + f) + (g + h2));
        }
        rs += __shfl_xor(rs, 32);
        s_ += rs;

        // P -> PV B-frags in registers: cvt_pk + permlane32_swap (layout identical to R15, proven)
        bf16x8 pb[4];
#pragma unroll
        for (int kvb = 0; kvb < 2; kvb++)
#pragma unroll
            for (int c = 0; c < 2; c++) {
                int base = c * 8;
                uint a0, a1, b0, b1;
                if (kvb == 0) {
                    a0 = pkbf16(c0[base + 0], c0[base + 1]); a1 = pkbf16(c0[base + 2], c0[base + 3]);
                    b0 = pkbf16(c0[base + 4], c0[base + 5]); b1 = pkbf16(c0[base + 6], c0[base + 7]);
                } else {
                    a0 = pkbf16(c1[base + 0], c1[base + 1]); a1 = pkbf16(c1[base + 2], c1[base + 3]);
                    b0 = pkbf16(c1[base + 4], c1[base + 5]); b1 = pkbf16(c1[base + 6], c1[base + 7]);
                }
                asm volatile("v_permlane32_swap_b32 %0, %1" : "+v"(a0), "+v"(b0));
                asm volatile("v_permlane32_swap_b32 %0, %1" : "+v"(a1), "+v"(b1));
                u32x4 wrd = {a0, a1, b0, b1};
                pb[kvb * 2 + c] = __builtin_bit_cast(bf16x8, wrd);
            }

        // PV on tile tt
        __builtin_amdgcn_s_setprio(1);
#pragma unroll
        for (int kvchunk = 0; kvchunk < 4; kvchunk++) {
            int kvc = kvchunk * 2 + hi;
            bf16x8 vf0 = *(const bf16x8*)&Vs[tt & 3][(kvc * 64 + ll) * 8];
            bf16x8 vf1 = *(const bf16x8*)&Vs[tt & 3][(kvc * 64 + 32 + ll) * 8];
            o0 = __builtin_amdgcn_mfma_f32_32x32x16_bf16(vf0, pb[kvchunk], o0, 0, 0, 0);
            o1 = __builtin_amdgcn_mfma_f32_32x32x16_bf16(vf1, pb[kvchunk], o1, 0, 0, 0);
        }
        __builtin_amdgcn_s_setprio(0);
    };

    for (int tt = 0; tt < NT2; tt += 2) {    // unroll-2: static reg-buffer indexing (rule #20)
        body(stA0, stA1, stB0, stB1, tt);
        body(stB0, stB1, stA0, stA1, tt + 1);
    }

    ushort* Og = ob + (size_t)b * NQ * INNER + h * DH;
    float inv = 1.f / s_;
    int q = q0 + w * 32 + ll;
#pragma unroll
    for (int rq = 0; rq < 4; rq++) {
        int d0 = 8 * rq + 4 * hi;
        uint2 pw;
        pw.x = pkbf16(o0[4 * rq + 0] * inv, o0[4 * rq + 1] * inv);
        pw.y = pkbf16(o0[4 * rq + 2] * inv, o0[4 * rq + 3] * inv);
        *(uint2*)&Og[(size_t)q * INNER + d0] = pw;
        uint2 pw1;
        pw1.x = pkbf16(o1[4 * rq + 0] * inv, o1[4 * rq + 1] * inv);
        pw1.y = pkbf16(o1[4 * rq + 2] * inv, o1[4 * rq + 3] * inv);
        *(uint2*)&Og[(size_t)q * INNER + 32 + d0] = pw1;
    }
}

extern "C" void kernel_launch(void* const* d_in, const int* in_sizes, int n_in,
                              void* d_out, int out_size, void* d_ws, size_t ws_size,
                              hipStream_t stream) {
    const float* x    = (const float*)d_in[0];
    const float* ctx  = (const float*)d_in[1];
    const float* Wq   = (const float*)d_in[2];
    const float* Wkv  = (const float*)d_in[3];
    const float* Wout = (const float*)d_in[4];
    const float* bout = (const float*)d_in[5];
    float* out = (float*)d_out;

    if (ws_size < (size_t)(56u << 20)) return;  // need 56MB scratch
    char* ws = (char*)d_ws;
    ushort* xb    = (ushort*)(ws);                 // 8MB
    ushort* cb    = (ushort*)(ws + (8u << 20));    // 8MB, dead after gemm_qkv
    ushort* ob    = (ushort*)(ws + (8u << 20));    // reuse cb slot
    ushort* qb    = (ushort*)(ws + (16u << 20));
    ushort* kb    = (ushort*)(ws + (24u << 20));
    ushort* vtb   = (ushort*)(ws + (32u << 20));   // v written directly transposed
    ushort* Wqt   = (ushort*)(ws + (48u << 20));
    ushort* Wkvt  = (ushort*)(ws + (50u << 20));
    ushort* Woutt = (ushort*)(ws + (54u << 20));

    prep<<<dim3(32, 32, 5), dim3(32, 8), 0, stream>>>(x, ctx, Wq, Wkv, Wout, xb, cb, Wqt, Wkvt, Woutt);
    // fused q-proj (scaled by 0.125*log2e) + kv-proj (v written transposed)
    gemm_qkv<<<768, 256, 0, stream>>>(xb, cb, Wqt, Wkvt, qb, kb, vtb, 0.125f * 1.44269504f);
    attn7<<<512, 256, 0, stream>>>(qb, kb, vtb, ob);
    gemm_out<<<512, 256, 0, stream>>>(ob, Woutt, out, bout);
}

// Round 17
// 163.794 us; speedup vs baseline: 1.0258x; 1.0258x over previous
//
#include <hip/hip_runtime.h>
#include <hip/hip_bf16.h>
#include <stdint.h>

#define NQ 2048
#define NKV 2048
#define DIM 1024
#define INNER 1024
#define HEADS 16
#define DH 64
#define BATCH 2

typedef float f32x4 __attribute__((ext_vector_type(4)));
typedef float f32x16 __attribute__((ext_vector_type(16)));
typedef __bf16 bf16x8 __attribute__((ext_vector_type(8)));
typedef unsigned int u32x4 __attribute__((ext_vector_type(4)));

__device__ inline ushort f2b(float f) {
    uint32_t u = __builtin_bit_cast(uint32_t, f);
    u += 0x7fff + ((u >> 16) & 1);   // round-to-nearest-even
    return (ushort)(u >> 16);
}

__device__ inline uint pkbf16(float lo, float hi) {
    __hip_bfloat162 h = __float22bfloat162_rn(make_float2(lo, hi));
    uint r;
    __builtin_memcpy(&r, &h, 4);   // low 16 = bf16(lo), high 16 = bf16(hi)
    return r;
}

__device__ __forceinline__ void gload16(const void* g, void* lds) {
    __builtin_amdgcn_global_load_lds(
        (const __attribute__((address_space(1))) unsigned int*)g,
        (__attribute__((address_space(3))) unsigned int*)lds, 16, 0, 0);
}

// ---------------- fused prep: z<4 -> weight transpose+cvt slices; z==4 -> x/ctx convert ----------------
__global__ void prep(const float* __restrict__ x, const float* __restrict__ ctx,
                     const float* __restrict__ Wq, const float* __restrict__ Wkv,
                     const float* __restrict__ Wout,
                     ushort* __restrict__ xb, ushort* __restrict__ cb,
                     ushort* __restrict__ Wqt, ushort* __restrict__ Wkvt,
                     ushort* __restrict__ Woutt) {
    int z = blockIdx.z;
    if (z < 4) {
        __shared__ ushort tile[32][33];
        const float* src; ushort* dst; int C;
        if (z == 0)      { src = Wq;          dst = Wqt;                C = 1024; }
        else if (z == 1) { src = Wkv;         dst = Wkvt;               C = 2048; }
        else if (z == 2) { src = Wkv + 1024;  dst = Wkvt + 1024 * 1024; C = 2048; }
        else             { src = Wout;        dst = Woutt;              C = 1024; }
        int c0 = blockIdx.x * 32, r0 = blockIdx.y * 32;
        int tx = threadIdx.x, ty = threadIdx.y;   // 32 x 8
#pragma unroll
        for (int i = 0; i < 4; i++)
            tile[ty + i * 8][tx] = f2b(src[(size_t)(r0 + ty + i * 8) * C + c0 + tx]);
        __syncthreads();
#pragma unroll
        for (int i = 0; i < 4; i++)
            dst[(size_t)(c0 + ty + i * 8) * 1024 + r0 + tx] = tile[tx][ty + i * 8];
    } else {
        const int n4 = (BATCH * NQ * DIM) / 4;   // float4 count per tensor
        int fb = blockIdx.y * 32 + blockIdx.x;   // 0..1023
        int t = threadIdx.y * 32 + threadIdx.x;  // 0..255
        for (int i = fb * 256 + t; i < 2 * n4; i += 1024 * 256) {
            float4 v;
            if (i < n4) v = ((const float4*)x)[i];
            else        v = ((const float4*)ctx)[i - n4];
            ushort4 o;
            o.x = f2b(v.x); o.y = f2b(v.y); o.z = f2b(v.z); o.w = f2b(v.w);
            if (i < n4) ((ushort4*)xb)[i] = o;
            else        ((ushort4*)cb)[i - n4] = o;
        }
    }
}

// ---------------- fused q/kv GEMM: 768 blocks of 128x128, K=1024, triple-buffer 2-deep prefetch ----------------
__global__ __launch_bounds__(256) void gemm_qkv(const ushort* __restrict__ xb, const ushort* __restrict__ cb,
                                                const ushort* __restrict__ Wqt, const ushort* __restrict__ Wkvt,
                                                ushort* __restrict__ qb, ushort* __restrict__ kb,
                                                ushort* __restrict__ vtb, float qscale) {
    constexpr int K = 1024, NT = 32;
    __shared__ ushort lds[24576];   // 48KB: 3 bufs x (A 8KB + B 8KB); v-epilogue tile [128][136] reuses
    int flat = blockIdx.x;
    int swz = (flat & 7) * 96 + (flat >> 3);      // XCD-chunked, bijective (768 % 8 == 0)
    bool isq = swz < 256;
    const ushort *A, *Bt;
    int m0, n0;
    if (isq) { A = xb; Bt = Wqt;  m0 = (swz >> 3) * 128;  n0 = (swz & 7) * 128; }
    else     { int b2 = swz - 256; A = cb; Bt = Wkvt; m0 = (b2 >> 4) * 128; n0 = (b2 & 15) * 128; }
    int t = threadIdx.x, l = t & 63, w = t >> 6;
    int wr = w >> 1, wc = w & 1;
    int lg = l >> 4, lc = l & 15;
    f32x4 acc[4][4] = {};

    auto stage = [&](int buf, int k0) {
#pragma unroll
        for (int i = 0; i < 2; i++) {
            int s = w + i * 4;
            gload16(A + (size_t)(m0 + (s & 1) * 64 + l) * K + k0 + (s >> 1) * 8, &lds[buf * 8192 + s * 512]);
            gload16(Bt + (size_t)(n0 + (s & 1) * 64 + l) * K + k0 + (s >> 1) * 8, &lds[buf * 8192 + 4096 + s * 512]);
        }
    };

    stage(0, 0);
    stage(1, 32);
    for (int tt = 0; tt < NT; ++tt) {
        int cur = tt % 3;
        if (tt + 2 < NT) {
            stage((tt + 2) % 3, (tt + 2) * 32);   // 2-deep prefetch, stays in flight
            asm volatile("s_waitcnt vmcnt(8)" ::: "memory");   // oldest 4 (cur tile) done
        } else if (tt + 1 < NT) {
            asm volatile("s_waitcnt vmcnt(4)" ::: "memory");
        } else {
            asm volatile("s_waitcnt vmcnt(0)" ::: "memory");
        }
        __builtin_amdgcn_s_barrier();
        asm volatile("" ::: "memory");
        bf16x8 af[4], bf[4];
#pragma unroll
        for (int mi = 0; mi < 4; mi++)
            af[mi] = *(const bf16x8*)&lds[cur * 8192 + (lg * 128 + wr * 64 + mi * 16 + lc) * 8];
#pragma unroll
        for (int ni = 0; ni < 4; ni++)
            bf[ni] = *(const bf16x8*)&lds[cur * 8192 + 4096 + (lg * 128 + wc * 64 + ni * 16 + lc) * 8];
        __builtin_amdgcn_s_setprio(1);
#pragma unroll
        for (int mi = 0; mi < 4; mi++)
#pragma unroll
            for (int ni = 0; ni < 4; ni++)
                acc[mi][ni] = __builtin_amdgcn_mfma_f32_16x16x32_bf16(af[mi], bf[ni], acc[mi][ni], 0, 0, 0);
        __builtin_amdgcn_s_setprio(0);
        asm volatile("s_waitcnt lgkmcnt(0)" ::: "memory");
        __builtin_amdgcn_s_barrier();
        asm volatile("" ::: "memory");
    }
    if (isq) {
#pragma unroll
        for (int mi = 0; mi < 4; mi++)
#pragma unroll
            for (int ni = 0; ni < 4; ni++)
#pragma unroll
                for (int r = 0; r < 4; r++) {
                    int m = m0 + wr * 64 + mi * 16 + lg * 4 + r;
                    int n = n0 + wc * 64 + ni * 16 + lc;
                    qb[(size_t)m * 1024 + n] = f2b(acc[mi][ni][r] * qscale);
                }
    } else if (n0 < 1024) {      // k half: row-major
#pragma unroll
        for (int mi = 0; mi < 4; mi++)
#pragma unroll
            for (int ni = 0; ni < 4; ni++)
#pragma unroll
                for (int r = 0; r < 4; r++) {
                    int m = m0 + wr * 64 + mi * 16 + lg * 4 + r;
                    int n = n0 + wc * 64 + ni * 16 + lc;
                    kb[(size_t)m * 1024 + n] = f2b(acc[mi][ni][r]);
                }
    } else {                     // v half: LDS transpose -> coalesced vtb[b][h][d][kv] stores
        int b = m0 >> 11, kv0 = m0 & 2047;
        int h0 = (n0 - 1024) >> 6;                // block covers heads h0, h0+1
#pragma unroll
        for (int mi = 0; mi < 4; mi++)
#pragma unroll
            for (int ni = 0; ni < 4; ni++)
#pragma unroll
                for (int r = 0; r < 4; r++) {
                    int ml = wr * 64 + mi * 16 + lg * 4 + r;    // kv-local 0..127
                    int nl = wc * 64 + ni * 16 + lc;            // n-local 0..127
                    lds[nl * 136 + ml] = f2b(acc[mi][ni][r]);
                }
        __syncthreads();
#pragma unroll
        for (int c = 0; c < 8; c++) {
            int idx = c * 256 + t;            // 0..2047
            int rrow = idx >> 4;              // n-local 0..127
            int chunk = idx & 15;             // 16B chunk along kv
            int h = h0 + (rrow >> 6), d = rrow & 63;
            u32x4 v = *(u32x4*)&lds[rrow * 136 + chunk * 8];
            *(u32x4*)&vtb[(((size_t)b * HEADS + h) * DH + d) * (size_t)NKV + kv0 + chunk * 8] = v;
        }
    }
}

// ---------------- out-proj GEMM: 256 blocks of 128x128, triple-buffer 2-deep, f32 out + bias ----------------
__global__ __launch_bounds__(256) void gemm_out(const ushort* __restrict__ A, const ushort* __restrict__ Bt,
                                                float* __restrict__ C0, const float* __restrict__ bias) {
    constexpr int K = 1024, NT = 32;
    __shared__ ushort lds[24576];
    int flat = blockIdx.x;
    int swz = (flat & 7) * 32 + (flat >> 3);      // XCD-chunked (256 % 8 == 0)
    int m0 = (swz >> 3) * 128, n0 = (swz & 7) * 128;
    int t = threadIdx.x, l = t & 63, w = t >> 6;
    int wr = w >> 1, wc = w & 1;
    int lg = l >> 4, lc = l & 15;
    f32x4 acc[4][4] = {};

    auto stage = [&](int buf, int k0) {
#pragma unroll
        for (int i = 0; i < 2; i++) {
            int s = w + i * 4;
            gload16(A + (size_t)(m0 + (s & 1) * 64 + l) * K + k0 + (s >> 1) * 8, &lds[buf * 8192 + s * 512]);
            gload16(Bt + (size_t)(n0 + (s & 1) * 64 + l) * K + k0 + (s >> 1) * 8, &lds[buf * 8192 + 4096 + s * 512]);
        }
    };

    stage(0, 0);
    stage(1, 32);
    for (int tt = 0; tt < NT; ++tt) {
        int cur = tt % 3;
        if (tt + 2 < NT) {
            stage((tt + 2) % 3, (tt + 2) * 32);
            asm volatile("s_waitcnt vmcnt(8)" ::: "memory");
        } else if (tt + 1 < NT) {
            asm volatile("s_waitcnt vmcnt(4)" ::: "memory");
        } else {
            asm volatile("s_waitcnt vmcnt(0)" ::: "memory");
        }
        __builtin_amdgcn_s_barrier();
        asm volatile("" ::: "memory");
        bf16x8 af[4], bf[4];
#pragma unroll
        for (int mi = 0; mi < 4; mi++)
            af[mi] = *(const bf16x8*)&lds[cur * 8192 + (lg * 128 + wr * 64 + mi * 16 + lc) * 8];
#pragma unroll
        for (int ni = 0; ni < 4; ni++)
            bf[ni] = *(const bf16x8*)&lds[cur * 8192 + 4096 + (lg * 128 + wc * 64 + ni * 16 + lc) * 8];
        __builtin_amdgcn_s_setprio(1);
#pragma unroll
        for (int mi = 0; mi < 4; mi++)
#pragma unroll
            for (int ni = 0; ni < 4; ni++)
                acc[mi][ni] = __builtin_amdgcn_mfma_f32_16x16x32_bf16(af[mi], bf[ni], acc[mi][ni], 0, 0, 0);
        __builtin_amdgcn_s_setprio(0);
        asm volatile("s_waitcnt lgkmcnt(0)" ::: "memory");
        __builtin_amdgcn_s_barrier();
        asm volatile("" ::: "memory");
    }
#pragma unroll
    for (int mi = 0; mi < 4; mi++)
#pragma unroll
        for (int ni = 0; ni < 4; ni++)
#pragma unroll
            for (int r = 0; r < 4; r++) {
                int m = m0 + wr * 64 + mi * 16 + lg * 4 + r;
                int n = n0 + wc * 64 + ni * 16 + lc;
                C0[(size_t)m * 1024 + n] = acc[mi][ni][r] + bias[n];
            }
}

// ---------------- flash attention v10: 32x32 MFMA, in-reg P, KV processed in 128-wide pairs ----------------
// QBLK=128 (4 waves x 32 q), 4-buffer K/V (pair {0,1} / {2,3}), ONE barrier + ONE vmcnt per 128 kv.
// Q frags direct from global. Swapped QK^T; P via cvt_pk + permlane32_swap. qb pre-scaled 0.125*log2e.
__global__ __launch_bounds__(256, 2) void attn8(const ushort* __restrict__ qb, const ushort* __restrict__ kb,
                                                const ushort* __restrict__ vtb, ushort* __restrict__ ob) {
    __shared__ ushort Ks[4][4096];       // [dc8][kv64][8] 8KB x4
    __shared__ ushort Vs[4][4096];       // [kvc8][d64][8] 8KB x4
    int flat = blockIdx.x;
    int swz = (flat & 7) * 64 + (flat >> 3);           // XCD-chunked (512 % 8 == 0)
    int qt = swz & 15, h = (swz >> 4) & 15, b = swz >> 8;
    int t = threadIdx.x, l = t & 63, w = t >> 6;
    int ll = l & 31, hi = l >> 5;
    const ushort* Qg = qb + (size_t)b * NQ * INNER + h * DH;
    const ushort* Kg = kb + (size_t)b * NKV * INNER + h * DH;
    const ushort* Vg = vtb + (((size_t)b * HEADS + h) * DH) * NKV;
    int q0 = qt * 128;
    constexpr int NP = NKV / 128;        // 16 pairs

    // Q fragments direct from global (one-time): q col = w*32+ll, d rows = (dchunk*2+hi)*8..+8
    bf16x8 qf[4];
#pragma unroll
    for (int dchunk = 0; dchunk < 4; dchunk++) {
        int dc = dchunk * 2 + hi;
        qf[dchunk] = *(const bf16x8*)&Qg[(size_t)(q0 + w * 32 + ll) * INNER + dc * 8];
    }
    auto stageKV = [&](int buf, int kv0) {
#pragma unroll
        for (int i = 0; i < 2; i++) {
            int s = w + i * 4;
            gload16(Kg + (size_t)(kv0 + l) * INNER + s * 8, &Ks[buf][s * 512]);
            gload16(Vg + (size_t)l * NKV + kv0 + s * 8, &Vs[buf][s * 512]);
        }
    };
    stageKV(0, 0); stageKV(1, 64);        // pair 0
    stageKV(2, 128); stageKV(3, 192);     // pair 1

    f32x16 o0 = {}, o1 = {};
    float m_ = -1e30f, s_ = 0.f;
    f32x16 zf = {};

    for (int tt = 0; tt < NP; ++tt) {
        int cur0 = (tt & 1) << 1;         // bufs {0,1} or {2,3}
        int cur1 = cur0 + 1;
        if (tt == 0) { asm volatile("s_waitcnt vmcnt(8)" ::: "memory"); }   // qf + pair0 landed
        else         { asm volatile("s_waitcnt vmcnt(0)" ::: "memory"); }   // pair tt landed
        __builtin_amdgcn_s_barrier();     // seals all waves' reads of pair tt-1 buffers
        asm volatile("" ::: "memory");
        if (tt + 1 < NP) {                // stage pair tt+1 into pair tt-1's buffers
            int nb0 = (cur0 ^ 2);
            stageKV(nb0, (tt + 1) * 128);
            stageKV(nb0 + 1, (tt + 1) * 128 + 64);
        }

        // QK^T both tiles: S^T[kv][q], 16 mfma
        f32x16 sA0 = zf, sA1 = zf, sB0 = zf, sB1 = zf;
        __builtin_amdgcn_s_setprio(1);
#pragma unroll
        for (int dchunk = 0; dchunk < 4; dchunk++) {
            int dc = dchunk * 2 + hi;
            bf16x8 ka0 = *(const bf16x8*)&Ks[cur0][(dc * 64 + ll) * 8];
            bf16x8 ka1 = *(const bf16x8*)&Ks[cur0][(dc * 64 + 32 + ll) * 8];
            bf16x8 kb0 = *(const bf16x8*)&Ks[cur1][(dc * 64 + ll) * 8];
            bf16x8 kb1 = *(const bf16x8*)&Ks[cur1][(dc * 64 + 32 + ll) * 8];
            sA0 = __builtin_amdgcn_mfma_f32_32x32x16_bf16(ka0, qf[dchunk], sA0, 0, 0, 0);
            sA1 = __builtin_amdgcn_mfma_f32_32x32x16_bf16(ka1, qf[dchunk], sA1, 0, 0, 0);
            sB0 = __builtin_amdgcn_mfma_f32_32x32x16_bf16(kb0, qf[dchunk], sB0, 0, 0, 0);
            sB1 = __builtin_amdgcn_mfma_f32_32x32x16_bf16(kb1, qf[dchunk], sB1, 0, 0, 0);
        }
        __builtin_amdgcn_s_setprio(0);

        // merged online softmax over 128 kv (lane owns q = w*32+ll; rows split lane l / l^32)
        float mx;
        {
            f32x16 m01 = __builtin_elementwise_max(__builtin_elementwise_max(sA0, sA1),
                                                   __builtin_elementwise_max(sB0, sB1));
            float a = fmaxf(fmaxf(m01[0], m01[1]), fmaxf(m01[2], m01[3]));
            float b2 = fmaxf(fmaxf(m01[4], m01[5]), fmaxf(m01[6], m01[7]));
            float c = fmaxf(fmaxf(m01[8], m01[9]), fmaxf(m01[10], m01[11]));
            float d = fmaxf(fmaxf(m01[12], m01[13]), fmaxf(m01[14], m01[15]));
            mx = fmaxf(fmaxf(a, b2), fmaxf(c, d));
        }
        mx = fmaxf(mx, __shfl_xor(mx, 32));
        if (!__all(mx - m_ <= 8.f)) {        // defer-max (T13)
            float mn2 = fmaxf(m_, mx);
            float fac = __builtin_amdgcn_exp2f(m_ - mn2);
            m_ = mn2; s_ *= fac; o0 *= fac; o1 *= fac;
        }
        float mn = m_;
#pragma unroll
        for (int r = 0; r < 16; r++) sA0[r] = __builtin_amdgcn_exp2f(sA0[r] - mn);
#pragma unroll
        for (int r = 0; r < 16; r++) sA1[r] = __builtin_amdgcn_exp2f(sA1[r] - mn);
#pragma unroll
        for (int r = 0; r < 16; r++) sB0[r] = __builtin_amdgcn_exp2f(sB0[r] - mn);
#pragma unroll
        for (int r = 0; r < 16; r++) sB1[r] = __builtin_amdgcn_exp2f(sB1[r] - mn);
        float rs;
        {
            f32x16 sm = (sA0 + sA1) + (sB0 + sB1);
            float a = (sm[0] + sm[1]) + (sm[2] + sm[3]);
            float b2 = (sm[4] + sm[5]) + (sm[6] + sm[7]);
            float c = (sm[8] + sm[9]) + (sm[10] + sm[11]);
            float d = (sm[12] + sm[13]) + (sm[14] + sm[15]);
            rs = (a + b2) + (c + d);
        }
        rs += __shfl_xor(rs, 32);
        s_ += rs;

        // P -> PV B-frags in registers (per 64-kv tile): cvt_pk + permlane32_swap (proven layout)
        bf16x8 pbA[4], pbB[4];
#pragma unroll
        for (int kvb = 0; kvb < 2; kvb++)
#pragma unroll
            for (int c = 0; c < 2; c++) {
                int base = c * 8;
                const f32x16& s0 = (kvb == 0) ? sA0 : sA1;
                uint a0 = pkbf16(s0[base + 0], s0[base + 1]);
                uint a1 = pkbf16(s0[base + 2], s0[base + 3]);
                uint b0 = pkbf16(s0[base + 4], s0[base + 5]);
                uint b1 = pkbf16(s0[base + 6], s0[base + 7]);
                asm volatile("v_permlane32_swap_b32 %0, %1" : "+v"(a0), "+v"(b0));
                asm volatile("v_permlane32_swap_b32 %0, %1" : "+v"(a1), "+v"(b1));
                u32x4 wrd = {a0, a1, b0, b1};
                pbA[kvb * 2 + c] = __builtin_bit_cast(bf16x8, wrd);
            }
#pragma unroll
        for (int kvb = 0; kvb < 2; kvb++)
#pragma unroll
            for (int c = 0; c < 2; c++) {
                int base = c * 8;
                const f32x16& s0 = (kvb == 0) ? sB0 : sB1;
                uint a0 = pkbf16(s0[base + 0], s0[base + 1]);
                uint a1 = pkbf16(s0[base + 2], s0[base + 3]);
                uint b0 = pkbf16(s0[base + 4], s0[base + 5]);
                uint b1 = pkbf16(s0[base + 6], s0[base + 7]);
                asm volatile("v_permlane32_swap_b32 %0, %1" : "+v"(a0), "+v"(b0));
                asm volatile("v_permlane32_swap_b32 %0, %1" : "+v"(a1), "+v"(b1));
                u32x4 wrd = {a0, a1, b0, b1};
                pbB[kvb * 2 + c] = __builtin_bit_cast(bf16x8, wrd);
            }

        // PV both tiles: 16 mfma
        __builtin_amdgcn_s_setprio(1);
#pragma unroll
        for (int kvchunk = 0; kvchunk < 4; kvchunk++) {
            int kvc = kvchunk * 2 + hi;
            bf16x8 va0 = *(const bf16x8*)&Vs[cur0][(kvc * 64 + ll) * 8];
            bf16x8 va1 = *(const bf16x8*)&Vs[cur0][(kvc * 64 + 32 + ll) * 8];
            o0 = __builtin_amdgcn_mfma_f32_32x32x16_bf16(va0, pbA[kvchunk], o0, 0, 0, 0);
            o1 = __builtin_amdgcn_mfma_f32_32x32x16_bf16(va1, pbA[kvchunk], o1, 0, 0, 0);
        }
#pragma unroll
        for (int kvchunk = 0; kvchunk < 4; kvchunk++) {
            int kvc = kvchunk * 2 + hi;
            bf16x8 vb0 = *(const bf16x8*)&Vs[cur1][(kvc * 64 + ll) * 8];
            bf16x8 vb1 = *(const bf16x8*)&Vs[cur1][(kvc * 64 + 32 + ll) * 8];
            o0 = __builtin_amdgcn_mfma_f32_32x32x16_bf16(vb0, pbB[kvchunk], o0, 0, 0, 0);
            o1 = __builtin_amdgcn_mfma_f32_32x32x16_bf16(vb1, pbB[kvchunk], o1, 0, 0, 0);
        }
        __builtin_amdgcn_s_setprio(0);
    }

    ushort* Og = ob + (size_t)b * NQ * INNER + h * DH;
    float inv = 1.f / s_;
    int q = q0 + w * 32 + ll;
#pragma unroll
    for (int rq = 0; rq < 4; rq++) {
        int d0 = 8 * rq + 4 * hi;
        uint2 pw;
        pw.x = pkbf16(o0[4 * rq + 0] * inv, o0[4 * rq + 1] * inv);
        pw.y = pkbf16(o0[4 * rq + 2] * inv, o0[4 * rq + 3] * inv);
        *(uint2*)&Og[(size_t)q * INNER + d0] = pw;
        uint2 pw1;
        pw1.x = pkbf16(o1[4 * rq + 0] * inv, o1[4 * rq + 1] * inv);
        pw1.y = pkbf16(o1[4 * rq + 2] * inv, o1[4 * rq + 3] * inv);
        *(uint2*)&Og[(size_t)q * INNER + 32 + d0] = pw1;
    }
}

extern "C" void kernel_launch(void* const* d_in, const int* in_sizes, int n_in,
                              void* d_out, int out_size, void* d_ws, size_t ws_size,
                              hipStream_t stream) {
    const float* x    = (const float*)d_in[0];
    const float* ctx  = (const float*)d_in[1];
    const float* Wq   = (const float*)d_in[2];
    const float* Wkv  = (const float*)d_in[3];
    const float* Wout = (const float*)d_in[4];
    const float* bout = (const float*)d_in[5];
    float* out = (float*)d_out;

    if (ws_size < (size_t)(56u << 20)) return;  // need 56MB scratch
    char* ws = (char*)d_ws;
    ushort* xb    = (ushort*)(ws);                 // 8MB
    ushort* cb    = (ushort*)(ws + (8u << 20));    // 8MB, dead after gemm_qkv
    ushort* ob    = (ushort*)(ws + (8u << 20));    // reuse cb slot
    ushort* qb    = (ushort*)(ws + (16u << 20));
    ushort* kb    = (ushort*)(ws + (24u << 20));
    ushort* vtb   = (ushort*)(ws + (32u << 20));   // v written directly transposed
    ushort* Wqt   = (ushort*)(ws + (48u << 20));
    ushort* Wkvt  = (ushort*)(ws + (50u << 20));
    ushort* Woutt = (ushort*)(ws + (54u << 20));

    prep<<<dim3(32, 32, 5), dim3(32, 8), 0, stream>>>(x, ctx, Wq, Wkv, Wout, xb, cb, Wqt, Wkvt, Woutt);
    // fused q-proj (scaled by 0.125*log2e) + kv-proj (v written transposed)
    gemm_qkv<<<768, 256, 0, stream>>>(xb, cb, Wqt, Wkvt, qb, kb, vtb, 0.125f * 1.44269504f);
    attn8<<<512, 256, 0, stream>>>(qb, kb, vtb, ob);
    gemm_out<<<256, 256, 0, stream>>>(ob, Woutt, out, bout);
}